// Round 1
// baseline (626.996 us; speedup 1.0000x reference)
//
#include <hip/hip_runtime.h>
#include <math.h>

#define BH_N 16
#define NCH  128
#define CS   32
#define DD   128
#define DP   132     // padded LDS row stride (bank stride 4, keeps 16B alignment)
#define SEQ  4096

// ws layout (floats):
//   gu  : [2048][32][128]  off 0          (8388608)
//   gw  : [2048][32][128]  off 8388608    (8388608)
//   gal : [2048][32][32]   off 16777216   (2097152)
//   giq : [16][4096]       off 18874368   (65536)
//   gik : [16][4096]       off 18939904   (65536)
// total 19005440 floats = 76,021,760 bytes

__device__ __forceinline__ float dot4(float4 a, float4 b) {
  return a.x*b.x + a.y*b.y + a.z*b.z + a.w*b.w;
}

__global__ __launch_bounds__(256) void p1_kernel(
    const float* __restrict__ gq, const float* __restrict__ gk,
    const float* __restrict__ gv, const float* __restrict__ gbeta,
    float* __restrict__ gu, float* __restrict__ gw, float* __restrict__ gal,
    float* __restrict__ giq, float* __restrict__ gik)
{
  __shared__ float qn[CS][DP];
  __shared__ float kn[CS][DP];
  __shared__ float vb[CS][DP];
  __shared__ float Amat[CS][CS];
  __shared__ float bet[CS];
  __shared__ float inq[CS], ink[CS];

  const int cid = blockIdx.x;          // bh*128 + ci
  const int bh  = cid >> 7;
  const int ci  = cid & 127;
  const int t   = threadIdx.x;
  const size_t base = ((size_t)bh * SEQ + (size_t)ci * CS) * DD;

  // ---- load raw chunk (32x128 each) ----
  for (int p = 0; p < 4; ++p) {
    int idx = t + (p << 8);            // float4 index 0..1023
    int rr  = idx >> 5;
    int c4  = (idx & 31) << 2;
    float4 qv = ((const float4*)(gq + base))[idx];
    float4 kv = ((const float4*)(gk + base))[idx];
    float4 vv = ((const float4*)(gv + base))[idx];
    *(float4*)&qn[rr][c4] = qv;
    *(float4*)&kn[rr][c4] = kv;
    *(float4*)&vb[rr][c4] = vv;
  }
  if (t < CS) bet[t] = gbeta[(size_t)bh * SEQ + ci * CS + t];
  __syncthreads();

  // ---- row norms: 8 threads per row ----
  {
    int rr  = t >> 3;
    int seg = (t & 7) << 4;
    float sq = 0.f, sk = 0.f;
    for (int j = 0; j < 16; j += 4) {
      float4 a = *(float4*)&qn[rr][seg + j];
      float4 b = *(float4*)&kn[rr][seg + j];
      sq += dot4(a, a);
      sk += dot4(b, b);
    }
    sq += __shfl_xor(sq, 1); sq += __shfl_xor(sq, 2); sq += __shfl_xor(sq, 4);
    sk += __shfl_xor(sk, 1); sk += __shfl_xor(sk, 2); sk += __shfl_xor(sk, 4);
    if ((t & 7) == 0) {
      float iq = 1.f / sqrtf(sq + 1e-6f);
      float ik = 1.f / sqrtf(sk + 1e-6f);
      inq[rr] = iq; ink[rr] = ik;
      giq[(size_t)bh * SEQ + ci * CS + rr] = iq;
      gik[(size_t)bh * SEQ + ci * CS + rr] = ik;
    }
  }
  __syncthreads();

  // ---- normalize qn,kn; scale vb by beta ----
  for (int p = 0; p < 4; ++p) {
    int idx = t + (p << 8);
    int rr  = idx >> 5;
    int c4  = (idx & 31) << 2;
    float iq = inq[rr], ik = ink[rr], bb = bet[rr];
    float4* pq = (float4*)&qn[rr][c4];
    float4* pk = (float4*)&kn[rr][c4];
    float4* pv = (float4*)&vb[rr][c4];
    float4 a = *pq; a.x*=iq; a.y*=iq; a.z*=iq; a.w*=iq; *pq = a;
    float4 b = *pk; b.x*=ik; b.y*=ik; b.z*=ik; b.w*=ik; *pk = b;
    float4 c = *pv; c.x*=bb; c.y*=bb; c.z*=bb; c.w*=bb; *pv = c;
  }
  __syncthreads();

  // ---- A = -(beta_i * kn_i . kn_j) strictly-lower; al = tril(qn kn^T) ----
  // thread: j = t&31, i in {t>>5 + 8p} -> shares kn[j] load across 4 pairs
  {
    const int j  = t & 31;
    const int i0 = t >> 5;
    float dk0=0,dk1=0,dk2=0,dk3=0;
    float dq0=0,dq1=0,dq2=0,dq3=0;
    for (int jj = 0; jj < DD; jj += 4) {
      float4 kj = *(float4*)&kn[j][jj];
      float4 ki, qi;
      ki = *(float4*)&kn[i0][jj];      qi = *(float4*)&qn[i0][jj];
      dk0 += dot4(ki, kj); dq0 += dot4(qi, kj);
      ki = *(float4*)&kn[i0+8][jj];    qi = *(float4*)&qn[i0+8][jj];
      dk1 += dot4(ki, kj); dq1 += dot4(qi, kj);
      ki = *(float4*)&kn[i0+16][jj];   qi = *(float4*)&qn[i0+16][jj];
      dk2 += dot4(ki, kj); dq2 += dot4(qi, kj);
      ki = *(float4*)&kn[i0+24][jj];   qi = *(float4*)&qn[i0+24][jj];
      dk3 += dot4(ki, kj); dq3 += dot4(qi, kj);
    }
    int i;
    i = i0;      Amat[i][j] = (j < i) ? (-bet[i]*dk0) : 0.f;
                 gal[(size_t)cid*1024 + i*32 + j] = (j <= i) ? dq0 : 0.f;
    i = i0+8;    Amat[i][j] = (j < i) ? (-bet[i]*dk1) : 0.f;
                 gal[(size_t)cid*1024 + i*32 + j] = (j <= i) ? dq1 : 0.f;
    i = i0+16;   Amat[i][j] = (j < i) ? (-bet[i]*dk2) : 0.f;
                 gal[(size_t)cid*1024 + i*32 + j] = (j <= i) ? dq2 : 0.f;
    i = i0+24;   Amat[i][j] = (j < i) ? (-bet[i]*dk3) : 0.f;
                 gal[(size_t)cid*1024 + i*32 + j] = (j <= i) ? dq3 : 0.f;
  }
  __syncthreads();

  // ---- UT transform (forward substitution), rows sequential ----
  for (int i = 1; i < CS; ++i) {
    float s0 = 0.f;
    if (t < CS) {
      s0 = Amat[i][t];
      for (int j = t + 1; j < i; ++j) s0 += Amat[i][j] * Amat[j][t];
    }
    __syncthreads();
    if (t < CS) Amat[i][t] = s0;
    __syncthreads();
  }
  if (t < CS) Amat[t][t] += 1.f;
  __syncthreads();

  // ---- kb = kn * beta (reuse qn buffer) ----
  for (int p = 0; p < 4; ++p) {
    int idx = t + (p << 8);
    int rr  = idx >> 5;
    int c4  = (idx & 31) << 2;
    float bb = bet[rr];
    float4 kv = *(float4*)&kn[rr][c4];
    kv.x*=bb; kv.y*=bb; kv.z*=bb; kv.w*=bb;
    *(float4*)&qn[rr][c4] = kv;
  }
  __syncthreads();

  // ---- u = A @ vb, w = A @ kb ----
  {
    const int cg = (t & 31) << 2;      // column group (4 cols)
    const int i0 = t >> 5;             // 0..7
    float4 au0=make_float4(0,0,0,0), au1=au0, au2=au0, au3=au0;
    float4 aw0=au0, aw1=au0, aw2=au0, aw3=au0;
    for (int j = 0; j < CS; ++j) {
      float4 vv = *(float4*)&vb[j][cg];
      float4 kk = *(float4*)&qn[j][cg];
      float a0 = Amat[i0][j], a1 = Amat[i0+8][j], a2 = Amat[i0+16][j], a3 = Amat[i0+24][j];
      au0.x += a0*vv.x; au0.y += a0*vv.y; au0.z += a0*vv.z; au0.w += a0*vv.w;
      au1.x += a1*vv.x; au1.y += a1*vv.y; au1.z += a1*vv.z; au1.w += a1*vv.w;
      au2.x += a2*vv.x; au2.y += a2*vv.y; au2.z += a2*vv.z; au2.w += a2*vv.w;
      au3.x += a3*vv.x; au3.y += a3*vv.y; au3.z += a3*vv.z; au3.w += a3*vv.w;
      aw0.x += a0*kk.x; aw0.y += a0*kk.y; aw0.z += a0*kk.z; aw0.w += a0*kk.w;
      aw1.x += a1*kk.x; aw1.y += a1*kk.y; aw1.z += a1*kk.z; aw1.w += a1*kk.w;
      aw2.x += a2*kk.x; aw2.y += a2*kk.y; aw2.z += a2*kk.z; aw2.w += a2*kk.w;
      aw3.x += a3*kk.x; aw3.y += a3*kk.y; aw3.z += a3*kk.z; aw3.w += a3*kk.w;
    }
    *(float4*)&gu[(size_t)cid*4096 + (i0   )*DD + cg] = au0;
    *(float4*)&gu[(size_t)cid*4096 + (i0+ 8)*DD + cg] = au1;
    *(float4*)&gu[(size_t)cid*4096 + (i0+16)*DD + cg] = au2;
    *(float4*)&gu[(size_t)cid*4096 + (i0+24)*DD + cg] = au3;
    *(float4*)&gw[(size_t)cid*4096 + (i0   )*DD + cg] = aw0;
    *(float4*)&gw[(size_t)cid*4096 + (i0+ 8)*DD + cg] = aw1;
    *(float4*)&gw[(size_t)cid*4096 + (i0+16)*DD + cg] = aw2;
    *(float4*)&gw[(size_t)cid*4096 + (i0+24)*DD + cg] = aw3;
  }
}

// Phase 2: sequential scan over 128 chunks. One block per (bh, dv-slice of 8).
// blockIdx: bh = blockIdx&15 (keeps all 16 slices of a bh on one XCD), s = blockIdx>>4.
__global__ __launch_bounds__(256) void p2_kernel(
    const float* __restrict__ gq, const float* __restrict__ gk,
    const float* __restrict__ gu, const float* __restrict__ gw,
    const float* __restrict__ gal,
    const float* __restrict__ giq, const float* __restrict__ gik,
    float* __restrict__ gout)
{
  __shared__ float wl[CS][DP];
  __shared__ float ql[CS][DP];
  __shared__ float kl[CS][DP];
  __shared__ float Sc[8][DP];      // S columns: Sc[cc][d], d=0..127
  __shared__ float ucol[8][36];    // u columns: ucol[cc][r]
  __shared__ float alt[CS][36];    // attn_local

  const int bh = blockIdx.x & 15;
  const int s  = blockIdx.x >> 4;  // dv slice 0..15
  const int t  = threadIdx.x;
  const int r  = t >> 3;           // 0..31 (chunk row / d-group)
  const int cc = t & 7;            // 0..7  (col within slice)

  for (int i = t; i < 8 * DP; i += 256) ((float*)Sc)[i] = 0.f;

  float* out_o = gout;
  float* out_S = gout + (size_t)BH_N * SEQ * DD;

  for (int ci = 0; ci < NCH; ++ci) {
    __syncthreads();   // prev iter's reads of wl/ql/kl/ucol done; Sc writes done
    const size_t base = ((size_t)bh * SEQ + (size_t)ci * CS) * DD;
    const size_t cof  = (size_t)(bh * NCH + ci) * 4096;

    for (int p = 0; p < 4; ++p) {
      int idx = t + (p << 8);
      int rr  = idx >> 5;
      int c4  = (idx & 31) << 2;
      float4 qv = ((const float4*)(gq + base))[idx];
      float4 kv = ((const float4*)(gk + base))[idx];
      float4 wv = ((const float4*)(gw + cof))[idx];
      float iq = giq[(size_t)bh * SEQ + ci * CS + rr];
      float ik = gik[(size_t)bh * SEQ + ci * CS + rr];
      qv.x*=iq; qv.y*=iq; qv.z*=iq; qv.w*=iq;
      kv.x*=ik; kv.y*=ik; kv.z*=ik; kv.w*=ik;
      *(float4*)&ql[rr][c4] = qv;
      *(float4*)&kl[rr][c4] = kv;
      *(float4*)&wl[rr][c4] = wv;
    }
    for (int p = 0; p < 4; ++p) {
      int idx = t + (p << 8);
      alt[idx >> 5][idx & 31] = gal[(size_t)(bh * NCH + ci) * 1024 + idx];
    }
    __syncthreads();

    // u[r,cc] = u0 - w[r,:].S[:,cc];  ao = q[r,:].S[:,cc]
    float au = 0.f, ao = 0.f;
    for (int j = 0; j < DD; j += 4) {
      float4 sv = *(float4*)&Sc[cc][j];
      float4 wv = *(float4*)&wl[r][j];
      float4 qv = *(float4*)&ql[r][j];
      au += dot4(wv, sv);
      ao += dot4(qv, sv);
    }
    float uval = gu[cof + r * DD + (s << 3) + cc] - au;
    ucol[cc][r] = uval;
    __syncthreads();   // all Sc reads done; ucol complete

    // o += attn_local[r,:] . u[:,cc]
    for (int j = 0; j < CS; j += 4) {
      float4 av = *(float4*)&alt[r][j];
      float4 uv = *(float4*)&ucol[cc][j];
      ao += dot4(av, uv);
    }
    out_o[base + r * DD + (s << 3) + cc] = ao;

    // S[4r..4r+3, cc] += sum_j kn[j, 4r..4r+3] * u[j, cc]
    float a0=0.f, a1=0.f, a2=0.f, a3=0.f;
    for (int j = 0; j < CS; ++j) {
      float4 kv = *(float4*)&kl[j][r << 2];
      float uu = ucol[cc][j];
      a0 += kv.x*uu; a1 += kv.y*uu; a2 += kv.z*uu; a3 += kv.w*uu;
    }
    float4* ps = (float4*)&Sc[cc][r << 2];
    float4 sold = *ps;
    sold.x += a0; sold.y += a1; sold.z += a2; sold.w += a3;
    *ps = sold;
  }

  __syncthreads();
  for (int idx = t; idx < 1024; idx += 256) {
    int d = idx >> 3, c8 = idx & 7;
    out_S[(size_t)bh * (DD * DD) + d * DD + (s << 3) + c8] = Sc[c8][d];
  }
}

extern "C" void kernel_launch(void* const* d_in, const int* in_sizes, int n_in,
                              void* d_out, int out_size, void* d_ws, size_t ws_size,
                              hipStream_t stream) {
  const float* q    = (const float*)d_in[0];
  const float* k    = (const float*)d_in[1];
  const float* v    = (const float*)d_in[2];
  const float* beta = (const float*)d_in[3];
  float* ws  = (float*)d_ws;
  float* gu  = ws;
  float* gw  = ws + 8388608;
  float* gal = ws + 16777216;
  float* giq = ws + 18874368;
  float* gik = ws + 18939904;
  float* out = (float*)d_out;

  p1_kernel<<<dim3(2048), dim3(256), 0, stream>>>(q, k, v, beta, gu, gw, gal, giq, gik);
  p2_kernel<<<dim3(256),  dim3(256), 0, stream>>>(q, k, gu, gw, gal, giq, gik, out);
}

// Round 2
// 563.583 us; speedup vs baseline: 1.1125x; 1.1125x over previous
//
#include <hip/hip_runtime.h>
#include <math.h>

typedef unsigned short u16;
typedef __attribute__((ext_vector_type(8))) short s8v;
typedef __attribute__((ext_vector_type(4))) float f4v;

#define BH 16
#define SEQ 4096
#define DD 128

__device__ __forceinline__ float b2f(u16 h){ union{unsigned u; float f;} v; v.u=((unsigned)h)<<16; return v.f; }
__device__ __forceinline__ u16 f2b(float f){ union{float f; unsigned u;} v; v.f=f; unsigned r=v.u+0x7FFFu+((v.u>>16)&1u); return (u16)(r>>16); }
__device__ __forceinline__ f4v mm16(s8v a, s8v b, f4v c){ return __builtin_amdgcn_mfma_f32_16x16x32_bf16(a,b,c,0,0,0); }

// ---------------------------------------------------------------------------
// Phase 1 (c=32): per chunk compute T=(I-strictlower(kb kn^T))^-1, AL=trilincl(qn kn^T),
// w=T kb, u0=T vb, qen=AL w - qn, p=AL u0.  Outputs bf16 (w,qen,u0) + fp32 p (into d_out).
// ---------------------------------------------------------------------------
__global__ __launch_bounds__(512) void p1_kernel(
    const float* __restrict__ gq, const float* __restrict__ gk,
    const float* __restrict__ gv, const float* __restrict__ gbeta,
    u16* __restrict__ gw, u16* __restrict__ gqen, u16* __restrict__ gu0,
    float* __restrict__ gik, float* __restrict__ gout)
{
  __shared__ float q32[32][132], k32[32][132], v32[32][132];
  __shared__ u16 knh[32][136], knl[32][136];
  __shared__ u16 qnh[32][136], qnl[32][136];
  __shared__ u16 kbh[32][136], kbl[32][136];
  __shared__ u16 vbT[128][40], kbT[128][40];
  __shared__ u16 wT[128][40], u0T[128][40];
  __shared__ float Amat[32][33];
  __shared__ u16 Tb[32][40], ALb[32][40];
  __shared__ float bet[32], inq[32], ink[32];

  const int cid = blockIdx.x, bh = cid>>7, ci = cid&127;
  const int t = threadIdx.x, wave = t>>6, lane = t&63, m = lane&15, qq = lane>>4;
  const size_t tokbase = (size_t)bh*SEQ + (size_t)ci*32;
  const size_t base = tokbase*DD;

  // 1: stage fp32 chunk
  for (int p=0;p<2;++p){
    int idx = t + (p<<9); int r = idx>>5, c4 = (idx&31)<<2;
    *(float4*)&q32[r][c4] = *(const float4*)(gq + base + r*DD + c4);
    *(float4*)&k32[r][c4] = *(const float4*)(gk + base + r*DD + c4);
    *(float4*)&v32[r][c4] = *(const float4*)(gv + base + r*DD + c4);
  }
  if (t<32) bet[t] = gbeta[tokbase + t];
  __syncthreads();

  // 2: row norms (8 threads per row)
  if (t<256){
    int rr = t>>3, seg = (t&7)<<4;
    float sq=0.f, sk=0.f;
    for(int j=0;j<16;j+=4){
      float4 a=*(float4*)&q32[rr][seg+j]; float4 b=*(float4*)&k32[rr][seg+j];
      sq += a.x*a.x+a.y*a.y+a.z*a.z+a.w*a.w;
      sk += b.x*b.x+b.y*b.y+b.z*b.z+b.w*b.w;
    }
    sq += __shfl_xor(sq,1); sq += __shfl_xor(sq,2); sq += __shfl_xor(sq,4);
    sk += __shfl_xor(sk,1); sk += __shfl_xor(sk,2); sk += __shfl_xor(sk,4);
    if((t&7)==0){
      float iq = 1.f/sqrtf(sq + 1e-6f);
      float ik = 1.f/sqrtf(sk + 1e-6f);
      inq[rr]=iq; ink[rr]=ik; gik[tokbase+rr]=ik;
    }
  }
  __syncthreads();

  // 3: build bf16 hi/lo arrays + transposed singles
  for (int p=0;p<2;++p){
    int idx = t + (p<<9); int r = idx>>5, c4 = (idx&31)<<2;
    float iq=inq[r], ik=ink[r], bb=bet[r];
    float4 qv=*(float4*)&q32[r][c4], kv=*(float4*)&k32[r][c4], vv=*(float4*)&v32[r][c4];
    float qa[4]={qv.x,qv.y,qv.z,qv.w}, ka[4]={kv.x,kv.y,kv.z,kv.w}, va[4]={vv.x,vv.y,vv.z,vv.w};
    union{u16 s[4]; uint2 v;} hq, lq, hk, lk, hb, lb;
    for(int i=0;i<4;++i){
      float qn = qa[i]*iq; u16 h1 = f2b(qn); hq.s[i]=h1; lq.s[i]=f2b(qn - b2f(h1));
      float kn = ka[i]*ik; u16 h2 = f2b(kn); hk.s[i]=h2; lk.s[i]=f2b(kn - b2f(h2));
      float kb = kn*bb;    u16 h3 = f2b(kb); hb.s[i]=h3; lb.s[i]=f2b(kb - b2f(h3));
      kbT[c4+i][r] = h3;
      vbT[c4+i][r] = f2b(va[i]*bb);
    }
    *(uint2*)&qnh[r][c4]=hq.v; *(uint2*)&qnl[r][c4]=lq.v;
    *(uint2*)&knh[r][c4]=hk.v; *(uint2*)&knl[r][c4]=lk.v;
    *(uint2*)&kbh[r][c4]=hb.v; *(uint2*)&kbl[r][c4]=lb.v;
  }
  __syncthreads();

  // 4: dk = kb kn^T (waves 0-3) / dq = qn kn^T (waves 4-7), hi/lo 3-term MFMA
  {
    int ww = wave & 3; int ti = ww>>1, tj = ww&1;
    f4v acc = {0.f,0.f,0.f,0.f};
    if (wave < 4){
      for(int kc=0;kc<4;++kc){
        int ko = kc*32 + qq*8;
        s8v ah = *(const s8v*)&kbh[ti*16+m][ko];
        s8v al = *(const s8v*)&kbl[ti*16+m][ko];
        s8v bhv = *(const s8v*)&knh[tj*16+m][ko];
        s8v blv = *(const s8v*)&knl[tj*16+m][ko];
        acc = mm16(ah,bhv,acc); acc = mm16(ah,blv,acc); acc = mm16(al,bhv,acc);
      }
      for(int r=0;r<4;++r){
        int row = ti*16 + qq*4 + r, col = tj*16 + m;
        Amat[row][col] = (col<row)? -acc[r] : 0.f;
      }
    } else {
      for(int kc=0;kc<4;++kc){
        int ko = kc*32 + qq*8;
        s8v ah = *(const s8v*)&qnh[ti*16+m][ko];
        s8v al = *(const s8v*)&qnl[ti*16+m][ko];
        s8v bhv = *(const s8v*)&knh[tj*16+m][ko];
        s8v blv = *(const s8v*)&knl[tj*16+m][ko];
        acc = mm16(ah,bhv,acc); acc = mm16(ah,blv,acc); acc = mm16(al,bhv,acc);
      }
      for(int r=0;r<4;++r){
        int row = ti*16 + qq*4 + r, col = tj*16 + m;
        ALb[row][col] = (col<=row)? f2b(acc[r]) : (u16)0;
      }
    }
  }
  __syncthreads();

  // 5: UT transform (forward substitution), single wave -> lockstep-safe
  if (t < 64 && lane < 32){
    const int L = lane;
    for (int i=1;i<32;++i){
      float s0 = Amat[i][L];
      for (int j=L+1;j<i;++j) s0 += Amat[i][j]*Amat[j][L];
      Amat[i][L] = s0;
    }
  }
  __syncthreads();
  // 5b: T (+I) -> bf16
  for(int p=0;p<2;++p){
    int idx = t + (p<<9); int row = idx>>5, col = idx&31;
    Tb[row][col] = f2b(Amat[row][col] + (row==col ? 1.f : 0.f));
  }
  __syncthreads();

  // 6: u0 = T vb (waves 0-3), w = T kb (waves 4-7)
  {
    bool isu = (wave<4); int w4 = wave&3;
    for (int tile = w4; tile < 16; tile += 4){
      int rt = tile>>3, dt = tile&7;
      s8v aT = *(const s8v*)&Tb[rt*16+m][qq*8];
      s8v bB = isu ? *(const s8v*)&vbT[dt*16+m][qq*8] : *(const s8v*)&kbT[dt*16+m][qq*8];
      f4v acc = {0.f,0.f,0.f,0.f};
      acc = mm16(aT,bB,acc);
      int tok0 = rt*16 + qq*4, dcol = dt*16+m;
      u16* gdst = isu ? gu0 : gw;
      u16 (*ldst)[40] = isu ? u0T : wT;
      union{u16 s[4]; uint2 v;} pk;
      for(int r=0;r<4;++r){
        u16 hv = f2b(acc[r]); pk.s[r]=hv;
        gdst[(tokbase + tok0 + r)*DD + dcol] = hv;
      }
      *(uint2*)&ldst[dcol][tok0] = pk.v;
    }
  }
  __syncthreads();

  // 7: qen = AL w - qn (waves 0-3), p = AL u0 (waves 4-7)
  {
    bool isq = (wave<4); int w4 = wave&3;
    for (int tile = w4; tile<16; tile+=4){
      int rt = tile>>3, dt = tile&7;
      s8v aA = *(const s8v*)&ALb[rt*16+m][qq*8];
      s8v bB = isq ? *(const s8v*)&wT[dt*16+m][qq*8] : *(const s8v*)&u0T[dt*16+m][qq*8];
      f4v acc = {0.f,0.f,0.f,0.f};
      acc = mm16(aA,bB,acc);
      int tok0 = rt*16+qq*4, dcol = dt*16+m;
      for(int r=0;r<4;++r){
        size_t gi = (tokbase+tok0+r)*DD + dcol;
        if (isq){
          float qn = b2f(qnh[tok0+r][dcol]) + b2f(qnl[tok0+r][dcol]);
          gqen[gi] = f2b(acc[r] - qn);
        } else {
          gout[gi] = acc[r];
        }
      }
    }
  }
}

// ---------------------------------------------------------------------------
// knT: normalized k transposed per 128-chunk, bf16 [d][j]
// ---------------------------------------------------------------------------
__global__ __launch_bounds__(256) void knt_kernel(
    const float* __restrict__ gk, const float* __restrict__ gik, u16* __restrict__ knT)
{
  __shared__ u16 kt[128][136];
  int blk = blockIdx.x, bh = blk>>5, ch = blk&31;
  int t = threadIdx.x;
  size_t tokb = (size_t)bh*SEQ + (size_t)ch*128;
  for(int p=0;p<16;++p){
    int idx = t + (p<<8); int j = idx>>5, c4 = (idx&31)<<2;
    float ik = gik[tokb + j];
    float4 kv = *(const float4*)(gk + (tokb+j)*DD + c4);
    kt[c4+0][j]=f2b(kv.x*ik); kt[c4+1][j]=f2b(kv.y*ik);
    kt[c4+2][j]=f2b(kv.z*ik); kt[c4+3][j]=f2b(kv.w*ik);
  }
  __syncthreads();
  u16* dst = knT + ((size_t)(bh*32+ch))*16384;
  for(int p=0;p<8;++p){
    int idx = t + (p<<8); int d = idx>>4, j8 = (idx&15)<<3;
    *(s8v*)(dst + d*128 + j8) = *(const s8v*)&kt[d][j8];
  }
}

// ---------------------------------------------------------------------------
// merge<C>: pairs of C-chunks -> 2C-chunks.  M_F = F2 k1n^T;  F2' = F2 - M_F w1;
// u02' = u02 - M_w u01;  p2' = p2 - M_qen u01.   (in place)
// ---------------------------------------------------------------------------
template<int C>
__global__ __launch_bounds__(256) void merge_kernel(
    const float* __restrict__ gk, const float* __restrict__ gik,
    u16* __restrict__ gw, u16* __restrict__ gqen, u16* __restrict__ gu0,
    float* __restrict__ gout)
{
  constexpr int P = 2048 / C;
  constexpr int SM = C + 8;
  __shared__ u16 k1[C][136];
  __shared__ u16 w1T[128][SM], u01T[128][SM];
  __shared__ u16 Mw[C][SM], MG[C][SM];
  const int bh = blockIdx.x / P, pr = blockIdx.x % P;
  const int t = threadIdx.x, wave = t>>6, lane = t&63, m = lane&15, qq = lane>>4;
  const int base1 = pr*2*C, base2 = base1 + C;
  const size_t tb1 = (size_t)bh*SEQ + base1, tb2 = (size_t)bh*SEQ + base2;

  // stage k1 (normalized, bf16 rows)
  for(int p=0;p<C*32/256;++p){
    int idx = t + (p<<8); int j = idx>>5, c4 = (idx&31)<<2;
    float ik = gik[tb1 + j];
    float4 kv = *(const float4*)(gk + (tb1+j)*DD + c4);
    union{u16 s[4]; uint2 v;} pk;
    pk.s[0]=f2b(kv.x*ik); pk.s[1]=f2b(kv.y*ik); pk.s[2]=f2b(kv.z*ik); pk.s[3]=f2b(kv.w*ik);
    *(uint2*)&k1[j][c4] = pk.v;
  }
  // stage w1T / u01T (transposed)
  for(int p=0;p<C*16/256;++p){
    int idx = t + (p<<8); int j = idx>>4, d8 = (idx&15)<<3;
    s8v wv = *(const s8v*)(gw + (tb1+j)*DD + d8);
    s8v uv = *(const s8v*)(gu0 + (tb1+j)*DD + d8);
    const u16* wsp = (const u16*)&wv; const u16* usp = (const u16*)&uv;
    for(int i=0;i<8;++i){ w1T[d8+i][j]=wsp[i]; u01T[d8+i][j]=usp[i]; }
  }
  __syncthreads();

  // M matrices
  constexpr int NT = (C/16)*(C/16);
  for(int tile = wave; tile < NT; tile += 4){
    int ti = tile/(C/16), tj = tile%(C/16);
    f4v aw = {0.f,0.f,0.f,0.f}, ag = {0.f,0.f,0.f,0.f};
    for(int kc=0;kc<4;++kc){
      int ko = kc*32 + qq*8;
      s8v b  = *(const s8v*)&k1[tj*16+m][ko];
      s8v a1 = *(const s8v*)(gw   + (tb2 + ti*16+m)*DD + ko);
      s8v a2 = *(const s8v*)(gqen + (tb2 + ti*16+m)*DD + ko);
      aw = mm16(a1,b,aw); ag = mm16(a2,b,ag);
    }
    for(int r=0;r<4;++r){
      Mw[ti*16+qq*4+r][tj*16+m] = f2b(aw[r]);
      MG[ti*16+qq*4+r][tj*16+m] = f2b(ag[r]);
    }
  }
  __syncthreads();

  // updates: wave 0: w2', 1: qen2', 2: u02', 3: p2'
  {
    const u16 (*Ma)[SM] = (wave==0||wave==2) ? Mw : MG;
    const u16 (*Bt)[SM] = (wave<2) ? w1T : u01T;
    for(int tile=0; tile<(C/16)*8; ++tile){
      int ti = tile>>3, dt = tile&7;
      f4v acc = {0.f,0.f,0.f,0.f};
      for(int kc=0;kc<C/32;++kc){
        int ko = kc*32+qq*8;
        s8v a = *(const s8v*)&Ma[ti*16+m][ko];
        s8v b = *(const s8v*)&Bt[dt*16+m][ko];
        acc = mm16(a,b,acc);
      }
      int d = dt*16+m;
      for(int r=0;r<4;++r){
        size_t gi = (tb2 + ti*16 + qq*4 + r)*DD + d;
        if (wave==0)      gw[gi]   = f2b(b2f(gw[gi])   - acc[r]);
        else if (wave==1) gqen[gi] = f2b(b2f(gqen[gi]) - acc[r]);
        else if (wave==2) gu0[gi]  = f2b(b2f(gu0[gi])  - acc[r]);
        else              gout[gi] = gout[gi] - acc[r];
      }
    }
  }
}

// ---------------------------------------------------------------------------
// Phase 2: scan over 32 chunks of 128.  Per step: u = u0 - w S; o = p - qen S;
// S += kn^T u.   S in per-wave acc regs (fp32), hi/lo bf16 through MFMA.
// 128 blocks = 8 dv-slices x 16 bh; 512 threads = 8 waves (wave w owns S rows 16w..16w+15).
// ---------------------------------------------------------------------------
__global__ __launch_bounds__(512) void p2_kernel(
    const u16* __restrict__ gw, const u16* __restrict__ gqen,
    const u16* __restrict__ gu0, const u16* __restrict__ knT,
    float* __restrict__ gout)
{
  __shared__ u16 lSb[2][16][136];
  __shared__ u16 lub[2][16][136];
  const int bh = blockIdx.x & 15, slice = blockIdx.x >> 4;
  const int t = threadIdx.x, wave = t>>6, lane = t&63, m = lane&15, qq = lane>>4;
  f4v S = {0.f,0.f,0.f,0.f};
  float* out_o = gout;
  float* out_S = gout + (size_t)BH*SEQ*DD;
  const size_t bhb = (size_t)bh*SEQ;

  for (int ci = 0; ci < 32; ++ci) {
    // (a) S -> lSb (hi/lo)
    {
      int d0 = wave*16 + qq*4;
      for(int r=0;r<4;++r){
        float v = S[r]; u16 hi = f2b(v); u16 lo = f2b(v - b2f(hi));
        lSb[0][m][d0+r] = hi; lSb[1][m][d0+r] = lo;
      }
    }
    __syncthreads();
    // (b) Y = W2 * S  (A-frags streamed from global)
    const u16* wbase = gw   + (bhb + (size_t)ci*128)*DD;
    const u16* qbase = gqen + (bhb + (size_t)ci*128)*DD;
    f4v au = {0.f,0.f,0.f,0.f}, ao = {0.f,0.f,0.f,0.f};
    for (int kc = 0; kc < 4; ++kc) {
      int ko = kc*32 + qq*8;
      s8v bhv = *(const s8v*)&lSb[0][m][ko];
      s8v blv = *(const s8v*)&lSb[1][m][ko];
      s8v awv = *(const s8v*)(wbase + (size_t)(wave*16 + m)*DD + ko);
      s8v aqv = *(const s8v*)(qbase + (size_t)(wave*16 + m)*DD + ko);
      au = mm16(awv,bhv,au); au = mm16(awv,blv,au);
      ao = mm16(aqv,bhv,ao); ao = mm16(aqv,blv,ao);
    }
    // (c) epilogue: u -> lub (hi/lo); o -> global
    {
      int tokb = ci*128 + wave*16 + qq*4;
      int dv = slice*16 + m;
      for(int r=0;r<4;++r){
        size_t gi = (bhb + tokb + r)*DD + dv;
        float uv = b2f(gu0[gi]) - au[r];
        u16 hi = f2b(uv); u16 lo = f2b(uv - b2f(hi));
        int j = wave*16 + qq*4 + r;
        lub[0][m][j] = hi; lub[1][m][j] = lo;
        out_o[gi] = out_o[gi] - ao[r];
      }
    }
    __syncthreads();
    // (d) S += kn^T u
    const u16* ktb = knT + ((size_t)(bh*32 + ci))*16384;
    for (int jc = 0; jc < 4; ++jc) {
      int ko = jc*32 + qq*8;
      s8v a   = *(const s8v*)(ktb + (size_t)(wave*16 + m)*DD + ko);
      s8v bhv = *(const s8v*)&lub[0][m][ko];
      s8v blv = *(const s8v*)&lub[1][m][ko];
      S = mm16(a,bhv,S); S = mm16(a,blv,S);
    }
  }
  // final S
  {
    int d0 = wave*16 + qq*4, dv = slice*16 + m;
    for(int r=0;r<4;++r)
      out_S[(size_t)bh*16384 + (size_t)(d0+r)*DD + dv] = S[r];
  }
}

extern "C" void kernel_launch(void* const* d_in, const int* in_sizes, int n_in,
                              void* d_out, int out_size, void* d_ws, size_t ws_size,
                              hipStream_t stream) {
  const float* q    = (const float*)d_in[0];
  const float* k    = (const float*)d_in[1];
  const float* v    = (const float*)d_in[2];
  const float* beta = (const float*)d_in[3];
  u16* wsu  = (u16*)d_ws;
  u16* gw   = wsu;
  u16* gqen = wsu + 8388608;
  u16* gu0  = wsu + 16777216;
  u16* knT  = wsu + 25165824;
  float* gik = (float*)(wsu + 33554432);
  float* out = (float*)d_out;

  p1_kernel<<<dim3(2048), dim3(512), 0, stream>>>(q, k, v, beta, gw, gqen, gu0, gik, out);
  knt_kernel<<<dim3(512), dim3(256), 0, stream>>>(k, gik, knT);
  merge_kernel<32><<<dim3(1024), dim3(256), 0, stream>>>(k, gik, gw, gqen, gu0, out);
  merge_kernel<64><<<dim3(512),  dim3(256), 0, stream>>>(k, gik, gw, gqen, gu0, out);
  p2_kernel<<<dim3(128), dim3(512), 0, stream>>>(gw, gqen, gu0, knT, out);
}

// Round 3
// 396.936 us; speedup vs baseline: 1.5796x; 1.4198x over previous
//
#include <hip/hip_runtime.h>
#include <math.h>

typedef unsigned short u16;
typedef __attribute__((ext_vector_type(8))) short s8v;
typedef __attribute__((ext_vector_type(4))) float f4v;

#define BH 16
#define SEQ 4096
#define DD 128

__device__ __forceinline__ float b2f(u16 h){ union{unsigned u; float f;} v; v.u=((unsigned)h)<<16; return v.f; }
__device__ __forceinline__ u16 f2b(float f){ union{float f; unsigned u;} v; v.f=f; unsigned r=v.u+0x7FFFu+((v.u>>16)&1u); return (u16)(r>>16); }
__device__ __forceinline__ f4v mm16(s8v a, s8v b, f4v c){ return __builtin_amdgcn_mfma_f32_16x16x32_bf16(a,b,c,0,0,0); }
__device__ __forceinline__ float dot4(float4 a, float4 b){ return a.x*b.x+a.y*b.y+a.z*b.z+a.w*b.w; }

// ---------------------------------------------------------------------------
// Phase 1 (c=32) per chunk: T=(I-strictlower(kb kn^T))^-1, AL=trilincl(qn kn^T),
// w=T kb, u0=T vb, qen=AL w - qn, p=AL u0.  Also emits knT (bf16, [d][token]).
// LDS 80,128 B -> 2 blocks/CU.  Substitution done in registers via shuffles.
// ---------------------------------------------------------------------------
__global__ __launch_bounds__(512,4) void p1_kernel(
    const float* __restrict__ gq, const float* __restrict__ gk,
    const float* __restrict__ gv, const float* __restrict__ gbeta,
    u16* __restrict__ gw, u16* __restrict__ gqen, u16* __restrict__ gu0,
    u16* __restrict__ gknT, float* __restrict__ gik, float* __restrict__ gout)
{
  __shared__ u16 qnh[32][136], qnl[32][136];   // 17408 B (live whole kernel)
  __shared__ u16 arena1[10240];                // 20480 B: knh/knl  ->  wT/u0T
  __shared__ u16 vbT[128][40], kbT[128][40];   // 20480 B
  __shared__ u16 arena2[8704];                 // 17408 B: vb16/kb16 -> Tb/ALb
  __shared__ float Amat[32][33];               // 4224 B
  __shared__ float bet[32];                    // 128 B

  u16 (*knh)[136] = (u16(*)[136])arena1;
  u16 (*knl)[136] = (u16(*)[136])(arena1+4352);
  u16 (*wTT)[40]  = (u16(*)[40])arena1;
  u16 (*u0T)[40]  = (u16(*)[40])(arena1+5120);
  u16 (*vb16)[136]= (u16(*)[136])arena2;
  u16 (*kb16)[136]= (u16(*)[136])(arena2+4352);
  u16 (*Tb)[40]   = (u16(*)[40])arena2;
  u16 (*ALb)[40]  = (u16(*)[40])(arena2+1280);

  const int cid = blockIdx.x, bh = cid>>7, ci = cid&127;
  const int t = threadIdx.x, wave = t>>6, lane = t&63, m = lane&15, qq = lane>>4;
  const size_t tokbase = (size_t)bh*SEQ + (size_t)ci*32;
  const size_t base = tokbase*DD;

  // ---- A: load q/k/v (coalesced float4), row norms via shfl, hi/lo convert ----
  for (int p=0;p<2;++p){
    int idx = t + (p<<9);
    int r = idx>>5, c4 = (idx&31)<<2;
    float4 qv = *(const float4*)(gq + base + r*DD + c4);
    float4 kv = *(const float4*)(gk + base + r*DD + c4);
    float4 vv = *(const float4*)(gv + base + r*DD + c4);
    float nq = dot4(qv,qv), nk = dot4(kv,kv);
    nq += __shfl_xor(nq,1); nq += __shfl_xor(nq,2); nq += __shfl_xor(nq,4);
    nq += __shfl_xor(nq,8); nq += __shfl_xor(nq,16);
    nk += __shfl_xor(nk,1); nk += __shfl_xor(nk,2); nk += __shfl_xor(nk,4);
    nk += __shfl_xor(nk,8); nk += __shfl_xor(nk,16);
    float iq = 1.f/sqrtf(nq+1e-6f), ik = 1.f/sqrtf(nk+1e-6f);
    float bb = gbeta[tokbase + r];
    if ((idx&31)==0){ gik[tokbase+r]=ik; bet[r]=bb; }
    float qa[4]={qv.x,qv.y,qv.z,qv.w}, ka[4]={kv.x,kv.y,kv.z,kv.w}, va[4]={vv.x,vv.y,vv.z,vv.w};
    union{u16 s[4]; uint2 v;} hq,lq,hk,lk,sv,sb;
    #pragma unroll
    for(int i=0;i<4;++i){
      float qn = qa[i]*iq; u16 h1=f2b(qn); hq.s[i]=h1; lq.s[i]=f2b(qn-b2f(h1));
      float kn = ka[i]*ik; u16 h2=f2b(kn); hk.s[i]=h2; lk.s[i]=f2b(kn-b2f(h2));
      sv.s[i]=f2b(va[i]*bb); sb.s[i]=f2b(kn*bb);
    }
    *(uint2*)&qnh[r][c4]=hq.v; *(uint2*)&qnl[r][c4]=lq.v;
    *(uint2*)&knh[r][c4]=hk.v; *(uint2*)&knl[r][c4]=lk.v;
    *(uint2*)&vb16[r][c4]=sv.v; *(uint2*)&kb16[r][c4]=sb.v;
  }
  __syncthreads();

  // ---- B: transposes (contiguous-lane writes, conflict-free) + knT global ----
  {
    u16* kdst = gknT + ((size_t)(bh*32 + (ci>>2)))*16384 + (size_t)((ci&3)*32);
    for (int g=0; g<2; ++g){
      int tau = t + (g<<9);
      int r = tau & 31, d0 = (tau>>5)<<2;
      union{u16 s[4]; uint2 v;} vv, kk, kn4;
      vv.v  = *(uint2*)&vb16[r][d0];
      kk.v  = *(uint2*)&kb16[r][d0];
      kn4.v = *(uint2*)&knh[r][d0];
      #pragma unroll
      for(int i=0;i<4;++i){
        vbT[d0+i][r] = vv.s[i];
        kbT[d0+i][r] = kk.s[i];
        kdst[(size_t)(d0+i)*128 + r] = kn4.s[i];
      }
    }
  }
  __syncthreads();

  // ---- C: G = kn kn^T (waves 0-2) -> Amat = -beta_i*G masked; AL (waves 3-5) ----
  {
    const int TI[3]={0,1,1}, TJ[3]={0,0,1};
    if (wave < 3){
      int ti=TI[wave], tj=TJ[wave];
      f4v acc = {0.f,0.f,0.f,0.f};
      #pragma unroll
      for(int kc=0;kc<4;++kc){
        int ko = kc*32 + qq*8;
        s8v ah = *(const s8v*)&knh[ti*16+m][ko];
        s8v al = *(const s8v*)&knl[ti*16+m][ko];
        s8v bhv = *(const s8v*)&knh[tj*16+m][ko];
        s8v blv = *(const s8v*)&knl[tj*16+m][ko];
        acc = mm16(ah,bhv,acc); acc = mm16(ah,blv,acc); acc = mm16(al,bhv,acc);
      }
      #pragma unroll
      for(int r=0;r<4;++r){
        int row = ti*16+qq*4+r, col = tj*16+m;
        Amat[row][col] = (col<row)? (-bet[row]*acc[r]) : 0.f;
      }
    } else if (wave < 6){
      int ti=TI[wave-3], tj=TJ[wave-3];
      f4v acc = {0.f,0.f,0.f,0.f};
      #pragma unroll
      for(int kc=0;kc<4;++kc){
        int ko = kc*32 + qq*8;
        s8v ah = *(const s8v*)&qnh[ti*16+m][ko];
        s8v al = *(const s8v*)&qnl[ti*16+m][ko];
        s8v bhv = *(const s8v*)&knh[tj*16+m][ko];
        s8v blv = *(const s8v*)&knl[tj*16+m][ko];
        acc = mm16(ah,bhv,acc); acc = mm16(ah,blv,acc); acc = mm16(al,bhv,acc);
      }
      #pragma unroll
      for(int r=0;r<4;++r){
        int row = ti*16+qq*4+r, col = tj*16+m;
        ALb[row][col] = (col<=row)? f2b(acc[r]) : (u16)0;
      }
    } else if (wave == 6){
      #pragma unroll
      for(int r=0;r<4;++r) ALb[qq*4+r][16+m] = (u16)0;   // always-upper tile
    }
  }
  __syncthreads();

  // ---- D: forward substitution in registers (lane L = column L, shfl broadcast) ----
  if (t < 32){
    float a[32];
    #pragma unroll
    for(int i=0;i<32;++i) a[i] = (t<i)? Amat[i][t] : 0.f;
    #pragma unroll
    for(int i=2;i<32;++i){
      float s = a[i];
      #pragma unroll
      for(int j=1;j<i;++j) s += __shfl(a[i],j)*a[j];
      a[i] = s;
    }
    #pragma unroll
    for(int i=0;i<32;++i) Tb[i][t] = f2b(a[i] + (i==t?1.f:0.f));
  }
  __syncthreads();

  // ---- E: u0 = T vb, w = T kb (32 tile-tasks over 8 waves) ----
  #pragma unroll
  for (int q8 = 0; q8 < 4; ++q8){
    int tau = wave + q8*8;              // 0..31
    bool isu = (tau < 16);
    int tile16 = tau & 15, rt = tile16>>3, dt = tile16&7;
    s8v aT = *(const s8v*)&Tb[rt*16+m][qq*8];
    s8v bB = isu ? *(const s8v*)&vbT[dt*16+m][qq*8] : *(const s8v*)&kbT[dt*16+m][qq*8];
    f4v acc = {0.f,0.f,0.f,0.f};
    acc = mm16(aT,bB,acc);
    int tok0 = rt*16 + qq*4, dcol = dt*16+m;
    u16* gdst = isu ? gu0 : gw;
    u16 (*ldst)[40] = isu ? u0T : wTT;
    union{u16 s[4]; uint2 v;} pk;
    #pragma unroll
    for(int r=0;r<4;++r){
      u16 hv = f2b(acc[r]); pk.s[r]=hv;
      gdst[(tokbase + tok0 + r)*DD + dcol] = hv;
    }
    *(uint2*)&ldst[dcol][tok0] = pk.v;
  }
  __syncthreads();

  // ---- F: qen = AL w - qn, p = AL u0 ----
  #pragma unroll
  for (int q8 = 0; q8 < 4; ++q8){
    int tau = wave + q8*8;
    bool isq = (tau < 16);
    int tile16 = tau & 15, rt = tile16>>3, dt = tile16&7;
    s8v aA = *(const s8v*)&ALb[rt*16+m][qq*8];
    s8v bB = isq ? *(const s8v*)&wTT[dt*16+m][qq*8] : *(const s8v*)&u0T[dt*16+m][qq*8];
    f4v acc = {0.f,0.f,0.f,0.f};
    acc = mm16(aA,bB,acc);
    int tok0 = rt*16+qq*4, dcol = dt*16+m;
    #pragma unroll
    for(int r=0;r<4;++r){
      size_t gi = (tokbase+tok0+r)*DD + dcol;
      if (isq){
        float qn = b2f(qnh[tok0+r][dcol]) + b2f(qnl[tok0+r][dcol]);
        gqen[gi] = f2b(acc[r] - qn);
      } else {
        gout[gi] = acc[r];
      }
    }
  }
}

// ---------------------------------------------------------------------------
// merge<C>: pairs of C-chunks -> 2C-chunks.  M_F = F2 k1n^T;  F2' = F2 - M_F w1;
// u02' = u02 - M_w u01;  p2' = p2 - M_qen u01.   (in place)
// ---------------------------------------------------------------------------
template<int C>
__global__ __launch_bounds__(256) void merge_kernel(
    const float* __restrict__ gk, const float* __restrict__ gik,
    u16* __restrict__ gw, u16* __restrict__ gqen, u16* __restrict__ gu0,
    float* __restrict__ gout)
{
  constexpr int P = 2048 / C;
  constexpr int SM = C + 8;
  __shared__ u16 k1[C][136];
  __shared__ u16 w1T[128][SM], u01T[128][SM];
  __shared__ u16 Mw[C][SM], MG[C][SM];
  const int bh = blockIdx.x / P, pr = blockIdx.x % P;
  const int t = threadIdx.x, wave = t>>6, lane = t&63, m = lane&15, qq = lane>>4;
  const int base1 = pr*2*C, base2 = base1 + C;
  const size_t tb1 = (size_t)bh*SEQ + base1, tb2 = (size_t)bh*SEQ + base2;

  for(int p=0;p<C*32/256;++p){
    int idx = t + (p<<8); int j = idx>>5, c4 = (idx&31)<<2;
    float ik = gik[tb1 + j];
    float4 kv = *(const float4*)(gk + (tb1+j)*DD + c4);
    union{u16 s[4]; uint2 v;} pk;
    pk.s[0]=f2b(kv.x*ik); pk.s[1]=f2b(kv.y*ik); pk.s[2]=f2b(kv.z*ik); pk.s[3]=f2b(kv.w*ik);
    *(uint2*)&k1[j][c4] = pk.v;
  }
  for(int p=0;p<C*16/256;++p){
    int idx = t + (p<<8); int j = idx>>4, d8 = (idx&15)<<3;
    s8v wv = *(const s8v*)(gw + (tb1+j)*DD + d8);
    s8v uv = *(const s8v*)(gu0 + (tb1+j)*DD + d8);
    const u16* wsp = (const u16*)&wv; const u16* usp = (const u16*)&uv;
    for(int i=0;i<8;++i){ w1T[d8+i][j]=wsp[i]; u01T[d8+i][j]=usp[i]; }
  }
  __syncthreads();

  constexpr int NT = (C/16)*(C/16);
  for(int tile = wave; tile < NT; tile += 4){
    int ti = tile/(C/16), tj = tile%(C/16);
    f4v aw = {0.f,0.f,0.f,0.f}, ag = {0.f,0.f,0.f,0.f};
    for(int kc=0;kc<4;++kc){
      int ko = kc*32 + qq*8;
      s8v b  = *(const s8v*)&k1[tj*16+m][ko];
      s8v a1 = *(const s8v*)(gw   + (tb2 + ti*16+m)*DD + ko);
      s8v a2 = *(const s8v*)(gqen + (tb2 + ti*16+m)*DD + ko);
      aw = mm16(a1,b,aw); ag = mm16(a2,b,ag);
    }
    for(int r=0;r<4;++r){
      Mw[ti*16+qq*4+r][tj*16+m] = f2b(aw[r]);
      MG[ti*16+qq*4+r][tj*16+m] = f2b(ag[r]);
    }
  }
  __syncthreads();

  {
    const u16 (*Ma)[SM] = (wave==0||wave==2) ? Mw : MG;
    const u16 (*Bt)[SM] = (wave<2) ? w1T : u01T;
    for(int tile=0; tile<(C/16)*8; ++tile){
      int ti = tile>>3, dt = tile&7;
      f4v acc = {0.f,0.f,0.f,0.f};
      for(int kc=0;kc<C/32;++kc){
        int ko = kc*32+qq*8;
        s8v a = *(const s8v*)&Ma[ti*16+m][ko];
        s8v b = *(const s8v*)&Bt[dt*16+m][ko];
        acc = mm16(a,b,acc);
      }
      int d = dt*16+m;
      for(int r=0;r<4;++r){
        size_t gi = (tb2 + ti*16 + qq*4 + r)*DD + d;
        if (wave==0)      gw[gi]   = f2b(b2f(gw[gi])   - acc[r]);
        else if (wave==1) gqen[gi] = f2b(b2f(gqen[gi]) - acc[r]);
        else if (wave==2) gu0[gi]  = f2b(b2f(gu0[gi])  - acc[r]);
        else              gout[gi] = gout[gi] - acc[r];
      }
    }
  }
}

// ---------------------------------------------------------------------------
// Phase 2: scan over 32 chunks of 128.  u = u0 - w S; o = p - qen S; S += kn^T u.
// ---------------------------------------------------------------------------
__global__ __launch_bounds__(512) void p2_kernel(
    const u16* __restrict__ gw, const u16* __restrict__ gqen,
    const u16* __restrict__ gu0, const u16* __restrict__ knT,
    float* __restrict__ gout)
{
  __shared__ u16 lSb[2][16][136];
  __shared__ u16 lub[2][16][136];
  const int bh = blockIdx.x & 15, slice = blockIdx.x >> 4;
  const int t = threadIdx.x, wave = t>>6, lane = t&63, m = lane&15, qq = lane>>4;
  f4v S = {0.f,0.f,0.f,0.f};
  float* out_o = gout;
  float* out_S = gout + (size_t)BH*SEQ*DD;
  const size_t bhb = (size_t)bh*SEQ;

  for (int ci = 0; ci < 32; ++ci) {
    {
      int d0 = wave*16 + qq*4;
      for(int r=0;r<4;++r){
        float v = S[r]; u16 hi = f2b(v); u16 lo = f2b(v - b2f(hi));
        lSb[0][m][d0+r] = hi; lSb[1][m][d0+r] = lo;
      }
    }
    __syncthreads();
    const u16* wbase = gw   + (bhb + (size_t)ci*128)*DD;
    const u16* qbase = gqen + (bhb + (size_t)ci*128)*DD;
    f4v au = {0.f,0.f,0.f,0.f}, ao = {0.f,0.f,0.f,0.f};
    for (int kc = 0; kc < 4; ++kc) {
      int ko = kc*32 + qq*8;
      s8v bhv = *(const s8v*)&lSb[0][m][ko];
      s8v blv = *(const s8v*)&lSb[1][m][ko];
      s8v awv = *(const s8v*)(wbase + (size_t)(wave*16 + m)*DD + ko);
      s8v aqv = *(const s8v*)(qbase + (size_t)(wave*16 + m)*DD + ko);
      au = mm16(awv,bhv,au); au = mm16(awv,blv,au);
      ao = mm16(aqv,bhv,ao); ao = mm16(aqv,blv,ao);
    }
    {
      int tokb = ci*128 + wave*16 + qq*4;
      int dv = slice*16 + m;
      for(int r=0;r<4;++r){
        size_t gi = (bhb + tokb + r)*DD + dv;
        float uv = b2f(gu0[gi]) - au[r];
        u16 hi = f2b(uv); u16 lo = f2b(uv - b2f(hi));
        int j = wave*16 + qq*4 + r;
        lub[0][m][j] = hi; lub[1][m][j] = lo;
        out_o[gi] = out_o[gi] - ao[r];
      }
    }
    __syncthreads();
    const u16* ktb = knT + ((size_t)(bh*32 + ci))*16384;
    for (int jc = 0; jc < 4; ++jc) {
      int ko = jc*32 + qq*8;
      s8v a   = *(const s8v*)(ktb + (size_t)(wave*16 + m)*DD + ko);
      s8v bhv = *(const s8v*)&lub[0][m][ko];
      s8v blv = *(const s8v*)&lub[1][m][ko];
      S = mm16(a,bhv,S); S = mm16(a,blv,S);
    }
  }
  {
    int d0 = wave*16 + qq*4, dv = slice*16 + m;
    for(int r=0;r<4;++r)
      out_S[(size_t)bh*16384 + (size_t)(d0+r)*DD + dv] = S[r];
  }
}

extern "C" void kernel_launch(void* const* d_in, const int* in_sizes, int n_in,
                              void* d_out, int out_size, void* d_ws, size_t ws_size,
                              hipStream_t stream) {
  const float* q    = (const float*)d_in[0];
  const float* k    = (const float*)d_in[1];
  const float* v    = (const float*)d_in[2];
  const float* beta = (const float*)d_in[3];
  u16* wsu  = (u16*)d_ws;
  u16* gw   = wsu;
  u16* gqen = wsu + 8388608;
  u16* gu0  = wsu + 16777216;
  u16* knT  = wsu + 25165824;
  float* gik = (float*)(wsu + 33554432);
  float* out = (float*)d_out;

  p1_kernel<<<dim3(2048), dim3(512), 0, stream>>>(q, k, v, beta, gw, gqen, gu0, knT, gik, out);
  merge_kernel<32><<<dim3(1024), dim3(256), 0, stream>>>(k, gik, gw, gqen, gu0, out);
  merge_kernel<64><<<dim3(512),  dim3(256), 0, stream>>>(k, gik, gw, gqen, gu0, out);
  p2_kernel<<<dim3(128), dim3(512), 0, stream>>>(gw, gqen, gu0, knT, out);
}

// Round 4
// 371.287 us; speedup vs baseline: 1.6887x; 1.0691x over previous
//
#include <hip/hip_runtime.h>
#include <math.h>

typedef unsigned short u16;
typedef __attribute__((ext_vector_type(8))) short s8v;
typedef __attribute__((ext_vector_type(4))) float f4v;

#define BH 16
#define SEQ 4096
#define DD 128

__device__ __forceinline__ float b2f(u16 h){ union{unsigned u; float f;} v; v.u=((unsigned)h)<<16; return v.f; }
__device__ __forceinline__ u16 f2b(float f){ union{float f; unsigned u;} v; v.f=f; unsigned r=v.u+0x7FFFu+((v.u>>16)&1u); return (u16)(r>>16); }
__device__ __forceinline__ f4v mm16(s8v a, s8v b, f4v c){ return __builtin_amdgcn_mfma_f32_16x16x32_bf16(a,b,c,0,0,0); }
__device__ __forceinline__ float dot4(float4 a, float4 b){ return a.x*b.x+a.y*b.y+a.z*b.z+a.w*b.w; }
// LDS-only barrier: p2's cross-wave traffic is LDS-only; global loads are
// lane-private, so no vmcnt drain needed -> prefetches stay in flight.
__device__ __forceinline__ void bar_lds(){
  asm volatile("s_waitcnt lgkmcnt(0)\n\ts_barrier" ::: "memory");
}

// ---------------------------------------------------------------------------
// Phase 1 (c=32) per chunk: T=(I-strictlower(kb kn^T))^-1, AL=trilincl(qn kn^T),
// w=T kb, u0=T vb, qen=AL w - qn, p=AL u0.  Also emits knT (bf16, [d][token]).
// ---------------------------------------------------------------------------
__global__ __launch_bounds__(512,4) void p1_kernel(
    const float* __restrict__ gq, const float* __restrict__ gk,
    const float* __restrict__ gv, const float* __restrict__ gbeta,
    u16* __restrict__ gw, u16* __restrict__ gqen, u16* __restrict__ gu0,
    u16* __restrict__ gknT, float* __restrict__ gik, float* __restrict__ gout)
{
  __shared__ u16 qnh[32][136], qnl[32][136];
  __shared__ u16 arena1[10240];
  __shared__ u16 vbT[128][40], kbT[128][40];
  __shared__ u16 arena2[8704];
  __shared__ float Amat[32][33];
  __shared__ float bet[32];

  u16 (*knh)[136] = (u16(*)[136])arena1;
  u16 (*knl)[136] = (u16(*)[136])(arena1+4352);
  u16 (*wTT)[40]  = (u16(*)[40])arena1;
  u16 (*u0T)[40]  = (u16(*)[40])(arena1+5120);
  u16 (*vb16)[136]= (u16(*)[136])arena2;
  u16 (*kb16)[136]= (u16(*)[136])(arena2+4352);
  u16 (*Tb)[40]   = (u16(*)[40])arena2;
  u16 (*ALb)[40]  = (u16(*)[40])(arena2+1280);

  const int cid = blockIdx.x, bh = cid>>7, ci = cid&127;
  const int t = threadIdx.x, wave = t>>6, lane = t&63, m = lane&15, qq = lane>>4;
  const size_t tokbase = (size_t)bh*SEQ + (size_t)ci*32;
  const size_t base = tokbase*DD;

  for (int p=0;p<2;++p){
    int idx = t + (p<<9);
    int r = idx>>5, c4 = (idx&31)<<2;
    float4 qv = *(const float4*)(gq + base + r*DD + c4);
    float4 kv = *(const float4*)(gk + base + r*DD + c4);
    float4 vv = *(const float4*)(gv + base + r*DD + c4);
    float nq = dot4(qv,qv), nk = dot4(kv,kv);
    nq += __shfl_xor(nq,1); nq += __shfl_xor(nq,2); nq += __shfl_xor(nq,4);
    nq += __shfl_xor(nq,8); nq += __shfl_xor(nq,16);
    nk += __shfl_xor(nk,1); nk += __shfl_xor(nk,2); nk += __shfl_xor(nk,4);
    nk += __shfl_xor(nk,8); nk += __shfl_xor(nk,16);
    float iq = 1.f/sqrtf(nq+1e-6f), ik = 1.f/sqrtf(nk+1e-6f);
    float bb = gbeta[tokbase + r];
    if ((idx&31)==0){ gik[tokbase+r]=ik; bet[r]=bb; }
    float qa[4]={qv.x,qv.y,qv.z,qv.w}, ka[4]={kv.x,kv.y,kv.z,kv.w}, va[4]={vv.x,vv.y,vv.z,vv.w};
    union{u16 s[4]; uint2 v;} hq,lq,hk,lk,sv,sb;
    #pragma unroll
    for(int i=0;i<4;++i){
      float qn = qa[i]*iq; u16 h1=f2b(qn); hq.s[i]=h1; lq.s[i]=f2b(qn-b2f(h1));
      float kn = ka[i]*ik; u16 h2=f2b(kn); hk.s[i]=h2; lk.s[i]=f2b(kn-b2f(h2));
      sv.s[i]=f2b(va[i]*bb); sb.s[i]=f2b(kn*bb);
    }
    *(uint2*)&qnh[r][c4]=hq.v; *(uint2*)&qnl[r][c4]=lq.v;
    *(uint2*)&knh[r][c4]=hk.v; *(uint2*)&knl[r][c4]=lk.v;
    *(uint2*)&vb16[r][c4]=sv.v; *(uint2*)&kb16[r][c4]=sb.v;
  }
  __syncthreads();

  {
    u16* kdst = gknT + ((size_t)(bh*32 + (ci>>2)))*16384 + (size_t)((ci&3)*32);
    for (int g=0; g<2; ++g){
      int tau = t + (g<<9);
      int r = tau & 31, d0 = (tau>>5)<<2;
      union{u16 s[4]; uint2 v;} vv, kk, kn4;
      vv.v  = *(uint2*)&vb16[r][d0];
      kk.v  = *(uint2*)&kb16[r][d0];
      kn4.v = *(uint2*)&knh[r][d0];
      #pragma unroll
      for(int i=0;i<4;++i){
        vbT[d0+i][r] = vv.s[i];
        kbT[d0+i][r] = kk.s[i];
        kdst[(size_t)(d0+i)*128 + r] = kn4.s[i];
      }
    }
  }
  __syncthreads();

  {
    const int TI[3]={0,1,1}, TJ[3]={0,0,1};
    if (wave < 3){
      int ti=TI[wave], tj=TJ[wave];
      f4v acc = {0.f,0.f,0.f,0.f};
      #pragma unroll
      for(int kc=0;kc<4;++kc){
        int ko = kc*32 + qq*8;
        s8v ah = *(const s8v*)&knh[ti*16+m][ko];
        s8v al = *(const s8v*)&knl[ti*16+m][ko];
        s8v bhv = *(const s8v*)&knh[tj*16+m][ko];
        s8v blv = *(const s8v*)&knl[tj*16+m][ko];
        acc = mm16(ah,bhv,acc); acc = mm16(ah,blv,acc); acc = mm16(al,bhv,acc);
      }
      #pragma unroll
      for(int r=0;r<4;++r){
        int row = ti*16+qq*4+r, col = tj*16+m;
        Amat[row][col] = (col<row)? (-bet[row]*acc[r]) : 0.f;
      }
    } else if (wave < 6){
      int ti=TI[wave-3], tj=TJ[wave-3];
      f4v acc = {0.f,0.f,0.f,0.f};
      #pragma unroll
      for(int kc=0;kc<4;++kc){
        int ko = kc*32 + qq*8;
        s8v ah = *(const s8v*)&qnh[ti*16+m][ko];
        s8v al = *(const s8v*)&qnl[ti*16+m][ko];
        s8v bhv = *(const s8v*)&knh[tj*16+m][ko];
        s8v blv = *(const s8v*)&knl[tj*16+m][ko];
        acc = mm16(ah,bhv,acc); acc = mm16(ah,blv,acc); acc = mm16(al,bhv,acc);
      }
      #pragma unroll
      for(int r=0;r<4;++r){
        int row = ti*16+qq*4+r, col = tj*16+m;
        ALb[row][col] = (col<=row)? f2b(acc[r]) : (u16)0;
      }
    } else if (wave == 6){
      #pragma unroll
      for(int r=0;r<4;++r) ALb[qq*4+r][16+m] = (u16)0;
    }
  }
  __syncthreads();

  if (t < 32){
    float a[32];
    #pragma unroll
    for(int i=0;i<32;++i) a[i] = (t<i)? Amat[i][t] : 0.f;
    #pragma unroll
    for(int i=2;i<32;++i){
      float s = a[i];
      #pragma unroll
      for(int j=1;j<i;++j) s += __shfl(a[i],j)*a[j];
      a[i] = s;
    }
    #pragma unroll
    for(int i=0;i<32;++i) Tb[i][t] = f2b(a[i] + (i==t?1.f:0.f));
  }
  __syncthreads();

  #pragma unroll
  for (int q8 = 0; q8 < 4; ++q8){
    int tau = wave + q8*8;
    bool isu = (tau < 16);
    int tile16 = tau & 15, rt = tile16>>3, dt = tile16&7;
    s8v aT = *(const s8v*)&Tb[rt*16+m][qq*8];
    s8v bB = isu ? *(const s8v*)&vbT[dt*16+m][qq*8] : *(const s8v*)&kbT[dt*16+m][qq*8];
    f4v acc = {0.f,0.f,0.f,0.f};
    acc = mm16(aT,bB,acc);
    int tok0 = rt*16 + qq*4, dcol = dt*16+m;
    u16* gdst = isu ? gu0 : gw;
    u16 (*ldst)[40] = isu ? u0T : wTT;
    union{u16 s[4]; uint2 v;} pk;
    #pragma unroll
    for(int r=0;r<4;++r){
      u16 hv = f2b(acc[r]); pk.s[r]=hv;
      gdst[(tokbase + tok0 + r)*DD + dcol] = hv;
    }
    *(uint2*)&ldst[dcol][tok0] = pk.v;
  }
  __syncthreads();

  #pragma unroll
  for (int q8 = 0; q8 < 4; ++q8){
    int tau = wave + q8*8;
    bool isq = (tau < 16);
    int tile16 = tau & 15, rt = tile16>>3, dt = tile16&7;
    s8v aA = *(const s8v*)&ALb[rt*16+m][qq*8];
    s8v bB = isq ? *(const s8v*)&wTT[dt*16+m][qq*8] : *(const s8v*)&u0T[dt*16+m][qq*8];
    f4v acc = {0.f,0.f,0.f,0.f};
    acc = mm16(aA,bB,acc);
    int tok0 = rt*16+qq*4, dcol = dt*16+m;
    #pragma unroll
    for(int r=0;r<4;++r){
      size_t gi = (tokbase+tok0+r)*DD + dcol;
      if (isq){
        float qn = b2f(qnh[tok0+r][dcol]) + b2f(qnl[tok0+r][dcol]);
        gqen[gi] = f2b(acc[r] - qn);
      } else {
        gout[gi] = acc[r];
      }
    }
  }
}

// ---------------------------------------------------------------------------
// merge<C>
// ---------------------------------------------------------------------------
template<int C>
__global__ __launch_bounds__(256) void merge_kernel(
    const float* __restrict__ gk, const float* __restrict__ gik,
    u16* __restrict__ gw, u16* __restrict__ gqen, u16* __restrict__ gu0,
    float* __restrict__ gout)
{
  constexpr int P = 2048 / C;
  constexpr int SM = C + 8;
  __shared__ u16 k1[C][136];
  __shared__ u16 w1T[128][SM], u01T[128][SM];
  __shared__ u16 Mw[C][SM], MG[C][SM];
  const int bh = blockIdx.x / P, pr = blockIdx.x % P;
  const int t = threadIdx.x, wave = t>>6, lane = t&63, m = lane&15, qq = lane>>4;
  const int base1 = pr*2*C, base2 = base1 + C;
  const size_t tb1 = (size_t)bh*SEQ + base1, tb2 = (size_t)bh*SEQ + base2;

  for(int p=0;p<C*32/256;++p){
    int idx = t + (p<<8); int j = idx>>5, c4 = (idx&31)<<2;
    float ik = gik[tb1 + j];
    float4 kv = *(const float4*)(gk + (tb1+j)*DD + c4);
    union{u16 s[4]; uint2 v;} pk;
    pk.s[0]=f2b(kv.x*ik); pk.s[1]=f2b(kv.y*ik); pk.s[2]=f2b(kv.z*ik); pk.s[3]=f2b(kv.w*ik);
    *(uint2*)&k1[j][c4] = pk.v;
  }
  for(int p=0;p<C*16/256;++p){
    int idx = t + (p<<8); int j = idx>>4, d8 = (idx&15)<<3;
    s8v wv = *(const s8v*)(gw + (tb1+j)*DD + d8);
    s8v uv = *(const s8v*)(gu0 + (tb1+j)*DD + d8);
    const u16* wsp = (const u16*)&wv; const u16* usp = (const u16*)&uv;
    for(int i=0;i<8;++i){ w1T[d8+i][j]=wsp[i]; u01T[d8+i][j]=usp[i]; }
  }
  __syncthreads();

  constexpr int NT = (C/16)*(C/16);
  for(int tile = wave; tile < NT; tile += 4){
    int ti = tile/(C/16), tj = tile%(C/16);
    f4v aw = {0.f,0.f,0.f,0.f}, ag = {0.f,0.f,0.f,0.f};
    for(int kc=0;kc<4;++kc){
      int ko = kc*32 + qq*8;
      s8v b  = *(const s8v*)&k1[tj*16+m][ko];
      s8v a1 = *(const s8v*)(gw   + (tb2 + ti*16+m)*DD + ko);
      s8v a2 = *(const s8v*)(gqen + (tb2 + ti*16+m)*DD + ko);
      aw = mm16(a1,b,aw); ag = mm16(a2,b,ag);
    }
    for(int r=0;r<4;++r){
      Mw[ti*16+qq*4+r][tj*16+m] = f2b(aw[r]);
      MG[ti*16+qq*4+r][tj*16+m] = f2b(ag[r]);
    }
  }
  __syncthreads();

  {
    const u16 (*Ma)[SM] = (wave==0||wave==2) ? Mw : MG;
    const u16 (*Bt)[SM] = (wave<2) ? w1T : u01T;
    for(int tile=0; tile<(C/16)*8; ++tile){
      int ti = tile>>3, dt = tile&7;
      f4v acc = {0.f,0.f,0.f,0.f};
      for(int kc=0;kc<C/32;++kc){
        int ko = kc*32+qq*8;
        s8v a = *(const s8v*)&Ma[ti*16+m][ko];
        s8v b = *(const s8v*)&Bt[dt*16+m][ko];
        acc = mm16(a,b,acc);
      }
      int d = dt*16+m;
      for(int r=0;r<4;++r){
        size_t gi = (tb2 + ti*16 + qq*4 + r)*DD + d;
        if (wave==0)      gw[gi]   = f2b(b2f(gw[gi])   - acc[r]);
        else if (wave==1) gqen[gi] = f2b(b2f(gqen[gi]) - acc[r]);
        else if (wave==2) gu0[gi]  = f2b(b2f(gu0[gi])  - acc[r]);
        else              gout[gi] = gout[gi] - acc[r];
      }
    }
  }
}

// ---------------------------------------------------------------------------
// Phase 2: scan over 32 chunks of 128.  u = u0 - w S; o = p - qen S; S += kn^T u.
// Software-pipelined: all global data for step ci+1 prefetched into registers
// during step ci; barriers are LDS-only so prefetch loads stay in flight.
// ---------------------------------------------------------------------------
__global__ __launch_bounds__(512) void p2_kernel(
    const u16* __restrict__ gw, const u16* __restrict__ gqen,
    const u16* __restrict__ gu0, const u16* __restrict__ knT,
    float* __restrict__ gout)
{
  __shared__ u16 lSb[2][16][136];
  __shared__ u16 lub[2][16][136];
  const int bh = blockIdx.x & 15, slice = blockIdx.x >> 4;
  const int t = threadIdx.x, wave = t>>6, lane = t&63, m = lane&15, qq = lane>>4;
  f4v S = {0.f,0.f,0.f,0.f};
  float* out_o = gout;
  float* out_S = gout + (size_t)BH*SEQ*DD;
  const size_t bhb = (size_t)bh*SEQ;
  const int dv = slice*16 + m;

  s8v wf[4], qf[4], kf[4];
  float u0f[4], pf[4];
  // prefetch step 0
  {
    const u16* wbase = gw   + bhb*DD + (size_t)(wave*16+m)*DD;
    const u16* qbase = gqen + bhb*DD + (size_t)(wave*16+m)*DD;
    const u16* ktb   = knT + ((size_t)(bh*32))*16384 + (size_t)(wave*16+m)*DD;
    #pragma unroll
    for(int kc=0;kc<4;++kc){
      wf[kc] = *(const s8v*)(wbase + kc*32 + qq*8);
      qf[kc] = *(const s8v*)(qbase + kc*32 + qq*8);
      kf[kc] = *(const s8v*)(ktb   + kc*32 + qq*8);
    }
    #pragma unroll
    for(int r=0;r<4;++r){
      size_t gi = (bhb + wave*16 + qq*4 + r)*DD + dv;
      u0f[r] = b2f(gu0[gi]);
      pf[r]  = out_o[gi];
    }
  }

  for (int ci = 0; ci < 32; ++ci) {
    // prefetch step ci+1 (wraps harmlessly at the end)
    s8v wn[4], qn4[4], kn4[4];
    float u0n[4], pn[4];
    {
      int cn = (ci + 1) & 31;
      const u16* wbase = gw   + (bhb + (size_t)cn*128)*DD + (size_t)(wave*16+m)*DD;
      const u16* qbase = gqen + (bhb + (size_t)cn*128)*DD + (size_t)(wave*16+m)*DD;
      const u16* ktb   = knT + ((size_t)(bh*32+cn))*16384 + (size_t)(wave*16+m)*DD;
      #pragma unroll
      for(int kc=0;kc<4;++kc){
        wn[kc]  = *(const s8v*)(wbase + kc*32 + qq*8);
        qn4[kc] = *(const s8v*)(qbase + kc*32 + qq*8);
        kn4[kc] = *(const s8v*)(ktb   + kc*32 + qq*8);
      }
      #pragma unroll
      for(int r=0;r<4;++r){
        size_t gi = (bhb + (size_t)cn*128 + wave*16 + qq*4 + r)*DD + dv;
        u0n[r] = b2f(gu0[gi]);
        pn[r]  = out_o[gi];
      }
    }

    // (a) S -> lSb (hi/lo)
    {
      int d0 = wave*16 + qq*4;
      #pragma unroll
      for(int r=0;r<4;++r){
        float v = S[r]; u16 hi = f2b(v); u16 lo = f2b(v - b2f(hi));
        lSb[0][m][d0+r] = hi; lSb[1][m][d0+r] = lo;
      }
    }
    bar_lds();
    // (b) au = w.S, ao = qen.S
    f4v au = {0.f,0.f,0.f,0.f}, ao = {0.f,0.f,0.f,0.f};
    #pragma unroll
    for (int kc = 0; kc < 4; ++kc) {
      int ko = kc*32 + qq*8;
      s8v bhv = *(const s8v*)&lSb[0][m][ko];
      s8v blv = *(const s8v*)&lSb[1][m][ko];
      au = mm16(wf[kc],bhv,au); au = mm16(wf[kc],blv,au);
      ao = mm16(qf[kc],bhv,ao); ao = mm16(qf[kc],blv,ao);
    }
    // (c) u = u0 - au -> lub (hi/lo); o = p - ao -> global
    {
      int j0 = wave*16 + qq*4;
      #pragma unroll
      for(int r=0;r<4;++r){
        size_t gi = (bhb + (size_t)ci*128 + j0 + r)*DD + dv;
        float uv = u0f[r] - au[r];
        u16 hi = f2b(uv); u16 lo = f2b(uv - b2f(hi));
        lub[0][m][j0+r] = hi; lub[1][m][j0+r] = lo;
        out_o[gi] = pf[r] - ao[r];
      }
    }
    bar_lds();
    // (d) S += kn^T u
    #pragma unroll
    for (int jc = 0; jc < 4; ++jc) {
      int ko = jc*32 + qq*8;
      s8v bhv = *(const s8v*)&lub[0][m][ko];
      s8v blv = *(const s8v*)&lub[1][m][ko];
      S = mm16(kf[jc],bhv,S); S = mm16(kf[jc],blv,S);
    }
    // rotate prefetch
    #pragma unroll
    for(int kc=0;kc<4;++kc){ wf[kc]=wn[kc]; qf[kc]=qn4[kc]; kf[kc]=kn4[kc]; }
    #pragma unroll
    for(int r=0;r<4;++r){ u0f[r]=u0n[r]; pf[r]=pn[r]; }
  }
  {
    int d0 = wave*16 + qq*4;
    #pragma unroll
    for(int r=0;r<4;++r)
      out_S[(size_t)bh*16384 + (size_t)(d0+r)*DD + dv] = S[r];
  }
}

extern "C" void kernel_launch(void* const* d_in, const int* in_sizes, int n_in,
                              void* d_out, int out_size, void* d_ws, size_t ws_size,
                              hipStream_t stream) {
  const float* q    = (const float*)d_in[0];
  const float* k    = (const float*)d_in[1];
  const float* v    = (const float*)d_in[2];
  const float* beta = (const float*)d_in[3];
  u16* wsu  = (u16*)d_ws;
  u16* gw   = wsu;
  u16* gqen = wsu + 8388608;
  u16* gu0  = wsu + 16777216;
  u16* knT  = wsu + 25165824;
  float* gik = (float*)(wsu + 33554432);
  float* out = (float*)d_out;

  p1_kernel<<<dim3(2048), dim3(512), 0, stream>>>(q, k, v, beta, gw, gqen, gu0, knT, gik, out);
  merge_kernel<32><<<dim3(1024), dim3(256), 0, stream>>>(k, gik, gw, gqen, gu0, out);
  merge_kernel<64><<<dim3(512),  dim3(256), 0, stream>>>(k, gik, gw, gqen, gu0, out);
  p2_kernel<<<dim3(128), dim3(512), 0, stream>>>(gw, gqen, gu0, knT, out);
}